// Round 1
// baseline (646.669 us; speedup 1.0000x reference)
//
#include <hip/hip_runtime.h>
#include <math.h>

#define NN 10000
#define NE 640000
#define H 128
#define H2 256
#define XD 8
#define ED 8
#define YD 112
#define NL 4
#define EPS_MSG 1e-7f
#define EPS_SM 1e-16f
#define EPS_LN 1e-5f
#define TN 16

// ---------- CSR build ----------
__global__ void hist_k(const int* __restrict__ dst, int* __restrict__ counts) {
    int e = blockIdx.x * 256 + threadIdx.x;
    if (e < NE) atomicAdd(&counts[dst[e]], 1);
}

__global__ void scan_k(const int* __restrict__ counts, int* __restrict__ rowptr) {
    __shared__ int part[1024];
    int tid = threadIdx.x;
    const int CH = (NN + 1023) / 1024;  // 10
    int base = tid * CH;
    int s = 0;
    for (int j = 0; j < CH; j++) { int i = base + j; if (i < NN) s += counts[i]; }
    part[tid] = s; __syncthreads();
    for (int off = 1; off < 1024; off <<= 1) {
        int v = (tid >= off) ? part[tid - off] : 0;
        __syncthreads();
        part[tid] += v;
        __syncthreads();
    }
    int run = part[tid] - s;  // exclusive prefix
    for (int j = 0; j < CH; j++) {
        int i = base + j;
        if (i < NN) { rowptr[i] = run; run += counts[i]; }
    }
    if (tid == 1023) rowptr[NN] = run;  // == NE
}

__global__ void scatter_k(const int* __restrict__ src, const int* __restrict__ dst,
                          const float* __restrict__ eattr, const int* __restrict__ rowptr,
                          int* __restrict__ fill, int* __restrict__ src_s,
                          float* __restrict__ ea_s) {
    int e = blockIdx.x * 256 + threadIdx.x;
    if (e >= NE) return;
    int d = dst[e];
    int pos = rowptr[d] + atomicAdd(&fill[d], 1);
    src_s[pos] = src[e];
    const float4* ein = (const float4*)eattr;
    float4* eout = (float4*)ea_s;
    eout[(size_t)pos * 2]     = ein[(size_t)e * 2];
    eout[(size_t)pos * 2 + 1] = ein[(size_t)e * 2 + 1];
}

// ---------- node encoder: h = x @ Wn + bn ----------
__global__ void node_enc_k(const float* __restrict__ x, const float* __restrict__ Wn,
                           const float* __restrict__ bn, float* __restrict__ h) {
    int n = blockIdx.x, c = threadIdx.x;
    __shared__ float xl[XD];
    if (c < XD) xl[c] = x[n * XD + c];
    __syncthreads();
    float acc = bn[c];
#pragma unroll
    for (int k = 0; k < XD; k++) acc = fmaf(xl[k], Wn[k * H + c], acc);
    h[(size_t)n * H + c] = acc;
}

// ---------- r = relu(node_ln(h)) ----------
__global__ void nodeln_k(const float* __restrict__ h, const float* __restrict__ g,
                         const float* __restrict__ b, float* __restrict__ r) {
    int n = blockIdx.x, c = threadIdx.x;  // 128 threads = 2 waves
    float v = h[(size_t)n * H + c];
    float s = v, s2 = v * v;
#pragma unroll
    for (int off = 32; off; off >>= 1) { s += __shfl_xor(s, off); s2 += __shfl_xor(s2, off); }
    __shared__ float red[4];
    int w = c >> 6;
    if ((c & 63) == 0) { red[w] = s; red[2 + w] = s2; }
    __syncthreads();
    float S = red[0] + red[1], S2 = red[2] + red[3];
    float m = S * (1.f / H);
    float var = S2 * (1.f / H) - m * m;
    float inv = rsqrtf(var + EPS_LN);
    float o = (v - m) * inv * g[c] + b[c];
    r[(size_t)n * H + c] = fmaxf(o, 0.f);
}

// ---------- per-node edge aggregation with online segment-softmax ----------
#define EB 32
__global__ void __launch_bounds__(128) edge_agg_k(
    const float* __restrict__ rin, const int* __restrict__ rowptr,
    const int* __restrict__ src_s, const float* __restrict__ ea_s,
    const float* __restrict__ We, const float* __restrict__ be,
    const float* __restrict__ tptr, int layer, float* __restrict__ agg) {
    int n = blockIdx.x, c = threadIdx.x;
    int beg = rowptr[n], end = rowptr[n + 1];
    float wcol[ED];
#pragma unroll
    for (int k = 0; k < ED; k++) wcol[k] = We[k * H + c];
    float bec = be[c];
    float ts = tptr[layer];
    float mx = -INFINITY, den = 0.f, num = 0.f;
    __shared__ float ebA[EB][ED];
    __shared__ int ebS[EB];
    for (int j0 = beg; j0 < end; j0 += EB) {
        int cnt = min(EB, end - j0);
        __syncthreads();
        for (int t = c; t < cnt * ED; t += 128) ((float*)ebA)[t] = ea_s[(size_t)j0 * ED + t];
        if (c < cnt) ebS[c] = src_s[j0 + c];
        __syncthreads();
        for (int j = 0; j < cnt; j++) {
            int sn = ebS[j];
            float ea = bec;
#pragma unroll
            for (int k = 0; k < ED; k++) ea = fmaf(ebA[j][k], wcol[k], ea);
            float hv = rin[(size_t)sn * H + c];
            float msg = fmaxf(hv + ea, 0.f) + EPS_MSG;
            float lg = msg * ts;
            float nmx = fmaxf(mx, lg);
            float sc = __expf(mx - nmx);   // exp(-inf)=0 handles first edge
            float p  = __expf(lg - nmx);
            den = den * sc + p;
            num = num * sc + p * msg;
            mx = nmx;
        }
    }
    agg[(size_t)n * H + c] = num / (den + EPS_SM) + rin[(size_t)n * H + c];
}

// ---------- y1 = agg @ W1[i] + b1[i], plus deterministic partial sums ----------
__global__ void __launch_bounds__(256) mm1_k(const float* __restrict__ agg,
    const float* __restrict__ W1i, const float* __restrict__ b1i,
    float* __restrict__ y1, float* __restrict__ part) {
    int nb = blockIdx.x, o = threadIdx.x;
    int n0 = nb * TN;
    __shared__ float a[TN][H];
    for (int t = o; t < TN * H; t += 256) ((float*)a)[t] = agg[(size_t)n0 * H + t];
    __syncthreads();
    float acc[TN];
#pragma unroll
    for (int i = 0; i < TN; i++) acc[i] = 0.f;
    for (int k = 0; k < H; k++) {
        float w = W1i[k * H2 + o];
#pragma unroll
        for (int i = 0; i < TN; i++) acc[i] = fmaf(a[i][k], w, acc[i]);
    }
    float bo = b1i[o];
    float ps = 0.f, ps2 = 0.f;
#pragma unroll
    for (int i = 0; i < TN; i++) {
        float v = acc[i] + bo;
        y1[(size_t)(n0 + i) * H2 + o] = v;
        ps += v; ps2 += v * v;
    }
#pragma unroll
    for (int off = 32; off; off >>= 1) { ps += __shfl_xor(ps, off); ps2 += __shfl_xor(ps2, off); }
    __shared__ float red[8];
    int w = o >> 6;
    if ((o & 63) == 0) { red[w] = ps; red[4 + w] = ps2; }
    __syncthreads();
    if (o == 0) {
        part[nb * 2]     = red[0] + red[1] + red[2] + red[3];
        part[nb * 2 + 1] = red[4] + red[5] + red[6] + red[7];
    }
}

// ---------- graph-LN stats finalize ----------
__global__ void stats_k(const float* __restrict__ part, int nb, float* __restrict__ stats) {
    int tid = threadIdx.x;  // 256
    float s = 0.f, s2 = 0.f;
    for (int i = tid; i < nb; i += 256) { s += part[2 * i]; s2 += part[2 * i + 1]; }
#pragma unroll
    for (int off = 32; off; off >>= 1) { s += __shfl_xor(s, off); s2 += __shfl_xor(s2, off); }
    __shared__ float red[8];
    int w = tid >> 6;
    if ((tid & 63) == 0) { red[w] = s; red[4 + w] = s2; }
    __syncthreads();
    if (tid == 0) {
        float S = red[0] + red[1] + red[2] + red[3];
        float S2 = red[4] + red[5] + red[6] + red[7];
        const float M = (float)NN * (float)H2;
        float m = S / M;
        float var = fmaxf(S2 / M - m * m, 0.f);
        stats[0] = m;
        stats[1] = 1.f / (sqrtf(var) + EPS_LN);
    }
}

// ---------- z = relu(graph_ln(y1)); h (+)= z @ W2[i] + b2[i] ----------
__global__ void __launch_bounds__(128) mm2_k(const float* __restrict__ y1,
    const float* __restrict__ g1i, const float* __restrict__ bt1i,
    const float* __restrict__ W2i, const float* __restrict__ b2i,
    const float* __restrict__ stats, float* __restrict__ h, int first) {
    int nb = blockIdx.x, o = threadIdx.x;
    int n0 = nb * TN;
    __shared__ float z[TN][H2];  // 16 KiB
    float m = stats[0], istd = stats[1];
    for (int t = o; t < TN * H2; t += 128) {
        int k = t & 255;
        float v = y1[(size_t)n0 * H2 + t];
        v = (v - m) * istd * g1i[k] + bt1i[k];
        ((float*)z)[t] = fmaxf(v, 0.f);
    }
    __syncthreads();
    float acc[TN];
#pragma unroll
    for (int i = 0; i < TN; i++) acc[i] = 0.f;
    for (int k = 0; k < H2; k++) {
        float w = W2i[k * H + o];
#pragma unroll
        for (int i = 0; i < TN; i++) acc[i] = fmaf(z[i][k], w, acc[i]);
    }
    float bo = b2i[o];
#pragma unroll
    for (int i = 0; i < TN; i++) {
        size_t idx = (size_t)(n0 + i) * H + o;
        float v = acc[i] + bo;
        h[idx] = first ? v : (h[idx] + v);
    }
}

// ---------- out = r @ Wout + bout ----------
__global__ void __launch_bounds__(128) mmout_k(const float* __restrict__ r,
    const float* __restrict__ Wout, const float* __restrict__ bout,
    float* __restrict__ out) {
    int nb = blockIdx.x, o = threadIdx.x;
    int n0 = nb * TN;
    __shared__ float a[TN][H];
    for (int t = o; t < TN * H; t += 128) ((float*)a)[t] = r[(size_t)n0 * H + t];
    __syncthreads();
    if (o < YD) {
        float acc[TN];
#pragma unroll
        for (int i = 0; i < TN; i++) acc[i] = 0.f;
        for (int k = 0; k < H; k++) {
            float w = Wout[k * YD + o];
#pragma unroll
            for (int i = 0; i < TN; i++) acc[i] = fmaf(a[i][k], w, acc[i]);
        }
        float bo = bout[o];
#pragma unroll
        for (int i = 0; i < TN; i++) out[(size_t)(n0 + i) * YD + o] = acc[i] + bo;
    }
}

extern "C" void kernel_launch(void* const* d_in, const int* in_sizes, int n_in,
                              void* d_out, int out_size, void* d_ws, size_t ws_size,
                              hipStream_t stream) {
    const float* x    = (const float*)d_in[0];
    const int*   ei   = (const int*)d_in[1];
    const float* eattr= (const float*)d_in[2];
    const float* Wn   = (const float*)d_in[3];
    const float* bn   = (const float*)d_in[4];
    const float* We   = (const float*)d_in[5];
    const float* be   = (const float*)d_in[6];
    const float* t    = (const float*)d_in[7];
    const float* W1   = (const float*)d_in[8];
    const float* b1   = (const float*)d_in[9];
    const float* g1   = (const float*)d_in[10];
    const float* bt1  = (const float*)d_in[11];
    const float* W2   = (const float*)d_in[12];
    const float* b2   = (const float*)d_in[13];
    const float* lng  = (const float*)d_in[14];
    const float* lnb  = (const float*)d_in[15];
    const float* Wout = (const float*)d_in[16];
    const float* bout = (const float*)d_in[17];
    float* out = (float*)d_out;

    const int* src = ei;        // edge_index[0]
    const int* dst = ei + NE;   // edge_index[1]

    char* ws = (char*)d_ws;
    size_t off = 0;
    auto alloc = [&](size_t bytes) -> char* {
        char* p = ws + off;
        off += (bytes + 255) & ~(size_t)255;
        return p;
    };
    int*   counts = (int*)alloc((size_t)NN * 4);
    int*   fill   = (int*)alloc((size_t)NN * 4);
    int*   rowptr = (int*)alloc((size_t)(NN + 1) * 4);
    int*   src_s  = (int*)alloc((size_t)NE * 4);
    float* ea_s   = (float*)alloc((size_t)NE * ED * 4);
    float* h      = (float*)alloc((size_t)NN * H * 4);
    float* r      = (float*)alloc((size_t)NN * H * 4);
    float* agg    = (float*)alloc((size_t)NN * H * 4);
    float* y1     = (float*)alloc((size_t)NN * H2 * 4);
    const int NB1 = NN / TN;  // 625 (exact)
    float* part   = (float*)alloc((size_t)NB1 * 2 * 4);
    float* stats  = (float*)alloc(2 * 4);
    (void)ws_size; (void)in_sizes; (void)n_in; (void)out_size;

    hipMemsetAsync(counts, 0, (size_t)NN * 4, stream);
    hipMemsetAsync(fill,   0, (size_t)NN * 4, stream);

    hist_k<<<(NE + 255) / 256, 256, 0, stream>>>(dst, counts);
    scan_k<<<1, 1024, 0, stream>>>(counts, rowptr);
    scatter_k<<<(NE + 255) / 256, 256, 0, stream>>>(src, dst, eattr, rowptr, fill, src_s, ea_s);
    node_enc_k<<<NN, H, 0, stream>>>(x, Wn, bn, h);

    for (int i = 0; i < NL; i++) {
        const float* cin = h;
        if (i > 0) {
            nodeln_k<<<NN, H, 0, stream>>>(h, lng + i * H, lnb + i * H, r);
            cin = r;
        }
        edge_agg_k<<<NN, H, 0, stream>>>(cin, rowptr, src_s, ea_s, We, be, t, i, agg);
        mm1_k<<<NB1, 256, 0, stream>>>(agg, W1 + (size_t)i * H * H2, b1 + i * H2, y1, part);
        stats_k<<<1, 256, 0, stream>>>(part, NB1, stats);
        mm2_k<<<NB1, 128, 0, stream>>>(y1, g1 + i * H2, bt1 + i * H2,
                                       W2 + (size_t)i * H2 * H, b2 + i * H, stats, h,
                                       (i == 0) ? 1 : 0);
    }
    nodeln_k<<<NN, H, 0, stream>>>(h, lng, lnb, r);  // layers[0] norm
    mmout_k<<<NB1, 128, 0, stream>>>(r, Wout, bout, out);
}